// Round 1
// baseline (1233.427 us; speedup 1.0000x reference)
//
#include <hip/hip_runtime.h>
#include <math.h>

// ---------------------------------------------------------------------------
// GCN(5 layers) + 1-step LSTM + FC head, f32, MI355X.
// Buffers in d_ws (floats): deg[N] | dinv[N] | hWs[N*64] | aggA[N*64] | aggB[N*64]
// hWs holds (h@W) * dinv[row]  (pre-scaled by source norm).
// agg init = hW*dinv^2 + b (self-loop + bias), then edge scatter atomics add
// hWs[row]*dinv[col]. ReLU is applied when the NEXT kernel loads the buffer.
// ---------------------------------------------------------------------------

#define DOUT 64

__global__ __launch_bounds__(256) void k_deg_init(float* __restrict__ deg, int n) {
    int i = blockIdx.x * 256 + threadIdx.x;
    if (i < n) deg[i] = 1.0f;   // self loop
}

__global__ __launch_bounds__(256) void k_deg_count(const int* __restrict__ col,
                                                   float* __restrict__ deg, int e) {
    int i = blockIdx.x * 256 + threadIdx.x;
    if (i < e) atomicAdd(&deg[col[i]], 1.0f);
}

__global__ __launch_bounds__(256) void k_dinv(const float* __restrict__ deg,
                                              float* __restrict__ dinv, int n) {
    int i = blockIdx.x * 256 + threadIdx.x;
    if (i < n) dinv[i] = rsqrtf(deg[i]);   // deg >= 1 always (self loop)
}

// GEMM: hW = (maybe-ReLU(X)) @ W.  Block = 256 threads = 4 waves, 16 nodes/block.
// Wave w computes nodes w*4..w*4+3; lane j = output column j.
// Also writes hWs = hW*dinv[n] and agg = hW*dinv[n]^2 + b.
template<int D, bool RELU_IN>
__global__ __launch_bounds__(256) void k_gemm(const float* __restrict__ X,
                                              const float* __restrict__ W,
                                              const float* __restrict__ b,
                                              const float* __restrict__ dinv,
                                              float* __restrict__ hWs,
                                              float* __restrict__ agg, int n) {
    __shared__ float Wl[D * DOUT];       // W[d][j]
    __shared__ float Xl[16 * D];         // 16 node rows
    const int t = threadIdx.x;
    const int n0 = blockIdx.x * 16;

    for (int i = t; i < D * DOUT; i += 256) Wl[i] = W[i];
    for (int i = t; i < 16 * D; i += 256) {
        int r = i / D;
        float v = 0.f;
        if (n0 + r < n) {
            v = X[(size_t)(n0 + r) * D + (i - r * D)];
            if (RELU_IN) v = fmaxf(v, 0.f);
        }
        Xl[i] = v;
    }
    __syncthreads();

    const int wv = t >> 6, lane = t & 63;
    const float* xb = &Xl[(wv * 4) * D];
    float acc[4] = {0.f, 0.f, 0.f, 0.f};

    #pragma unroll 4
    for (int d = 0; d < D; d += 4) {
        float4 x0 = *(const float4*)(xb + d);
        float4 x1 = *(const float4*)(xb + D + d);
        float4 x2 = *(const float4*)(xb + 2 * D + d);
        float4 x3 = *(const float4*)(xb + 3 * D + d);
        float w0 = Wl[(d + 0) * DOUT + lane];
        float w1 = Wl[(d + 1) * DOUT + lane];
        float w2 = Wl[(d + 2) * DOUT + lane];
        float w3 = Wl[(d + 3) * DOUT + lane];
        acc[0] = fmaf(x0.w, w3, fmaf(x0.z, w2, fmaf(x0.y, w1, fmaf(x0.x, w0, acc[0]))));
        acc[1] = fmaf(x1.w, w3, fmaf(x1.z, w2, fmaf(x1.y, w1, fmaf(x1.x, w0, acc[1]))));
        acc[2] = fmaf(x2.w, w3, fmaf(x2.z, w2, fmaf(x2.y, w1, fmaf(x2.x, w0, acc[2]))));
        acc[3] = fmaf(x3.w, w3, fmaf(x3.z, w2, fmaf(x3.y, w1, fmaf(x3.x, w0, acc[3]))));
    }

    const float bias = b[lane];
    #pragma unroll
    for (int k = 0; k < 4; k++) {
        int nn = n0 + wv * 4 + k;
        if (nn < n) {
            float di = dinv[nn];
            float hw = acc[k];
            hWs[(size_t)nn * DOUT + lane] = hw * di;
            agg[(size_t)nn * DOUT + lane] = fmaf(hw * di, di, bias);
        }
    }
}

// Edge scatter: one wave per edge, lane = feature dim.
// agg[col] += hWs[row] * dinv[col]
__global__ __launch_bounds__(256) void k_scatter(const int* __restrict__ row,
                                                 const int* __restrict__ col,
                                                 const float* __restrict__ dinv,
                                                 const float* __restrict__ hWs,
                                                 float* __restrict__ agg, int e) {
    const int lane = threadIdx.x & 63;
    int gw = (blockIdx.x * 256 + threadIdx.x) >> 6;
    const int nw = (gridDim.x * 256) >> 6;
    for (; gw < e; gw += nw) {
        int r = row[gw], c = col[gw];
        float v = hWs[(size_t)r * DOUT + lane] * dinv[c];
        atomicAdd(&agg[(size_t)c * DOUT + lane], v);
    }
}

__device__ __forceinline__ float sigm(float x) { return 1.f / (1.f + __expf(-x)); }
__device__ __forceinline__ float tanh_fast(float x) { return 1.f - 2.f / (__expf(2.f * x) + 1.f); }

// LSTM (1 step, h0=c0=0  =>  c1 = i*g, f-gate and W_hh dead) + FC head.
// One thread per node. W_ih rows for gates {i,g,o} staged in 4 LDS chunks of
// 32 k's each (96 rows x 64 = 24 KB). All LDS reads are wave-uniform broadcasts.
__global__ __launch_bounds__(256) void k_lstm_fc(const float* __restrict__ agg,
                                                 const float* __restrict__ W_ih,
                                                 const float* __restrict__ b_ih,
                                                 const float* __restrict__ b_hh,
                                                 const float* __restrict__ W_fc,
                                                 const float* __restrict__ b_fc,
                                                 float* __restrict__ out, int n) {
    __shared__ float Wl[96 * 64];     // 24 KB: rows {i,g,o} for current k-chunk
    __shared__ float Wfc[10 * 128];   // 5 KB
    __shared__ float bb[3 * 128];     // combined bias for i,g,o
    const int t = threadIdx.x;
    const int nn = blockIdx.x * 256 + t;

    for (int i = t; i < 10 * 128; i += 256) Wfc[i] = W_fc[i];
    for (int i = t; i < 3 * 128; i += 256) {
        int gsel = i >> 7;                       // 0,1,2 -> gates i,g,o
        int gate = (gsel == 0) ? 0 : (gsel + 1); // 0,2,3
        int k = i & 127;
        bb[i] = b_ih[gate * 128 + k] + b_hh[gate * 128 + k];
    }

    float h[64];
    if (nn < n) {
        const float4* hp = (const float4*)&agg[(size_t)nn * 64];
        #pragma unroll
        for (int i = 0; i < 16; i++) {
            float4 v = hp[i];
            h[4 * i + 0] = fmaxf(v.x, 0.f);
            h[4 * i + 1] = fmaxf(v.y, 0.f);
            h[4 * i + 2] = fmaxf(v.z, 0.f);
            h[4 * i + 3] = fmaxf(v.w, 0.f);
        }
    } else {
        #pragma unroll
        for (int i = 0; i < 64; i++) h[i] = 0.f;
    }

    float acc[10];
    #pragma unroll
    for (int c = 0; c < 10; c++) acc[c] = 0.f;

    for (int chunk = 0; chunk < 4; chunk++) {
        const int k0 = chunk * 32;
        __syncthreads();
        // stage 96 rows (i,g,o x 32 k's) of W_ih
        for (int i = t; i < 96 * 64; i += 256) {
            int lr = i >> 6;                        // 0..95
            int gsel = lr >> 5;                     // 0,1,2
            int gate = (gsel == 0) ? 0 : (gsel + 1);
            int kk = lr & 31;
            Wl[i] = W_ih[((size_t)(gate * 128 + k0 + kk)) * 64 + (i & 63)];
        }
        __syncthreads();

        for (int kk = 0; kk < 32; kk++) {
            int k = k0 + kk;
            float gi = bb[k], gg = bb[128 + k], go = bb[256 + k];
            const float4* wi = (const float4*)&Wl[(kk) * 64];
            const float4* wg = (const float4*)&Wl[(32 + kk) * 64];
            const float4* wo = (const float4*)&Wl[(64 + kk) * 64];
            #pragma unroll
            for (int d4 = 0; d4 < 16; d4++) {
                float4 a = wi[d4], gvec = wg[d4], o = wo[d4];
                float h0v = h[4 * d4 + 0], h1v = h[4 * d4 + 1];
                float h2v = h[4 * d4 + 2], h3v = h[4 * d4 + 3];
                gi = fmaf(h3v, a.w, fmaf(h2v, a.z, fmaf(h1v, a.y, fmaf(h0v, a.x, gi))));
                gg = fmaf(h3v, gvec.w, fmaf(h2v, gvec.z, fmaf(h1v, gvec.y, fmaf(h0v, gvec.x, gg))));
                go = fmaf(h3v, o.w, fmaf(h2v, o.z, fmaf(h1v, o.y, fmaf(h0v, o.x, go))));
            }
            float c1 = sigm(gi) * tanh_fast(gg);
            float h1 = sigm(go) * tanh_fast(c1);
            #pragma unroll
            for (int c = 0; c < 10; c++) acc[c] = fmaf(h1, Wfc[c * 128 + k], acc[c]);
        }
    }

    if (nn < n) {
        #pragma unroll
        for (int c = 0; c < 10; c++) out[(size_t)nn * 10 + c] = acc[c] + b_fc[c];
    }
}

extern "C" void kernel_launch(void* const* d_in, const int* in_sizes, int n_in,
                              void* d_out, int out_size, void* d_ws, size_t ws_size,
                              hipStream_t stream) {
    const float* x    = (const float*)d_in[0];
    const int*   ei   = (const int*)d_in[1];
    const float* W1   = (const float*)d_in[2];
    const float* b1   = (const float*)d_in[3];
    const float* W2   = (const float*)d_in[4];
    const float* b2   = (const float*)d_in[5];
    const float* W3   = (const float*)d_in[6];
    const float* b3   = (const float*)d_in[7];
    const float* W4   = (const float*)d_in[8];
    const float* b4   = (const float*)d_in[9];
    const float* W5   = (const float*)d_in[10];
    const float* b5   = (const float*)d_in[11];
    const float* W_ih = (const float*)d_in[12];
    // d_in[13] = W_hh: unused (h0 = 0)
    const float* b_ih = (const float*)d_in[14];
    const float* b_hh = (const float*)d_in[15];
    const float* W_fc = (const float*)d_in[16];
    const float* b_fc = (const float*)d_in[17];
    float* out = (float*)d_out;

    const int N = in_sizes[0] / 128;
    const int E = in_sizes[1] / 2;
    const int* row = ei;
    const int* col = ei + E;

    float* ws   = (float*)d_ws;
    float* deg  = ws;
    float* dinv = ws + N;
    float* hWs  = ws + 2 * (size_t)N;
    float* aggA = hWs + (size_t)N * DOUT;
    float* aggB = aggA + (size_t)N * DOUT;

    const int nbN = (N + 255) / 256;
    const int nbE = (E + 255) / 256;
    const int nbG = (N + 15) / 16;

    k_deg_init<<<nbN, 256, 0, stream>>>(deg, N);
    k_deg_count<<<nbE, 256, 0, stream>>>(col, deg, E);
    k_dinv<<<nbN, 256, 0, stream>>>(deg, dinv, N);

    // layer 1: x (D=128) -> aggA
    k_gemm<128, false><<<nbG, 256, 0, stream>>>(x, W1, b1, dinv, hWs, aggA, N);
    k_scatter<<<8192, 256, 0, stream>>>(row, col, dinv, hWs, aggA, E);
    // layer 2: relu(aggA) -> aggB
    k_gemm<64, true><<<nbG, 256, 0, stream>>>(aggA, W2, b2, dinv, hWs, aggB, N);
    k_scatter<<<8192, 256, 0, stream>>>(row, col, dinv, hWs, aggB, E);
    // layer 3: relu(aggB) -> aggA
    k_gemm<64, true><<<nbG, 256, 0, stream>>>(aggB, W3, b3, dinv, hWs, aggA, N);
    k_scatter<<<8192, 256, 0, stream>>>(row, col, dinv, hWs, aggA, E);
    // layer 4: relu(aggA) -> aggB
    k_gemm<64, true><<<nbG, 256, 0, stream>>>(aggA, W4, b4, dinv, hWs, aggB, N);
    k_scatter<<<8192, 256, 0, stream>>>(row, col, dinv, hWs, aggB, E);
    // layer 5: relu(aggB) -> aggA
    k_gemm<64, true><<<nbG, 256, 0, stream>>>(aggB, W5, b5, dinv, hWs, aggA, N);
    k_scatter<<<8192, 256, 0, stream>>>(row, col, dinv, hWs, aggA, E);

    // LSTM + FC: relu(aggA) -> out
    k_lstm_fc<<<nbN, 256, 0, stream>>>(aggA, W_ih, b_ih, b_hh, W_fc, b_fc, out, N);
}

// Round 5
// 778.126 us; speedup vs baseline: 1.5851x; 1.5851x over previous
//
#include <hip/hip_runtime.h>
#include <math.h>

#define DOUT 64

// ---------------------------------------------------------------------------
// GCN(5) + LSTM(1 step) + FC head, f32, MI355X.
// Pipeline per call:
//   memset cnt; transpose W1..W5 -> WT; count indeg; scan (rowptr/cursor/dinv);
//   fill CSR srcidx;  5x { gemm2 (X*dinv @ W -> hWs), gather (CSR sum -> agg) };
//   lstm_fc (wave = 8 nodes, lane = k; gate-chunked W_ih in swizzled LDS).
// h0=c0=0  =>  f-gate and W_hh are dead; c1 = i*g.
// ---------------------------------------------------------------------------

__global__ __launch_bounds__(256) void k_count(const int* __restrict__ col,
                                               int* __restrict__ cnt, int e) {
    int i = blockIdx.x * 256 + threadIdx.x;
    if (i < e) atomicAdd(&cnt[col[i]], 1);
}

__global__ __launch_bounds__(1024) void k_scan(const int* __restrict__ cnt,
                                               int* __restrict__ rowptr,
                                               int* __restrict__ cursor,
                                               float* __restrict__ dinv, int n) {
    __shared__ int part[1024];
    const int t = threadIdx.x;
    const int per = (n + 1023) >> 10;
    const int base = t * per;
    int s = 0;
    for (int i = 0; i < per; i++) { int idx = base + i; if (idx < n) s += cnt[idx]; }
    part[t] = s;
    __syncthreads();
    for (int off = 1; off < 1024; off <<= 1) {
        int v = 0;
        if (t >= off) v = part[t - off];
        __syncthreads();
        if (t >= off) part[t] += v;
        __syncthreads();
    }
    int run = (t > 0) ? part[t - 1] : 0;
    for (int i = 0; i < per; i++) {
        int idx = base + i;
        if (idx < n) {
            int c = cnt[idx];
            rowptr[idx] = run;
            cursor[idx] = run;
            dinv[idx] = rsqrtf((float)(c + 1));   // +1 self loop
            run += c;
        }
    }
    if (t == 1023) rowptr[n] = run;
}

__global__ __launch_bounds__(256) void k_fill(const int* __restrict__ row,
                                              const int* __restrict__ col,
                                              int* __restrict__ cursor,
                                              int* __restrict__ srcidx, int e) {
    int i = blockIdx.x * 256 + threadIdx.x;
    if (i < e) {
        int p = atomicAdd(&cursor[col[i]], 1);
        srcidx[p] = row[i];
    }
}

// Transpose all 5 GCN weights: WT[j][d] = W[d][j].  W1:128x64, W2..W5:64x64.
__global__ __launch_bounds__(256) void k_transp(const float* __restrict__ W1,
                                                const float* __restrict__ W2,
                                                const float* __restrict__ W3,
                                                const float* __restrict__ W4,
                                                const float* __restrict__ W5,
                                                float* __restrict__ WT) {
    int i = blockIdx.x * 256 + threadIdx.x;
    if (i < 8192) {
        int j = i >> 7, d = i & 127;
        WT[i] = W1[d * 64 + j];
    } else if (i < 24576) {
        int q = i - 8192;
        int w = q >> 12, r = q & 4095;
        int j = r >> 6, d = r & 63;
        const float* Ws = (w == 0) ? W2 : (w == 1) ? W3 : (w == 2) ? W4 : W5;
        WT[i] = Ws[d * 64 + j];
    }
}

// GEMM: hWs[node] = (relu?(X[node]) * dinv[node]) @ W.
// Block 256 = 4 waves, 8 nodes/wave (32/block). lane = output column.
// W in LDS column-major with XOR swizzle (worst 2-way conflict = free).
template<int D, bool RELU>
__global__ __launch_bounds__(256) void k_gemm2(const float* __restrict__ X,
                                               const float* __restrict__ WT,
                                               const float* __restrict__ dinv,
                                               float* __restrict__ hWs, int n) {
    constexpr int D4 = D / 4;
    __shared__ float Wls[64 * D];
    __shared__ float Xls[32 * D];
    const int t = threadIdx.x;
    const int node0 = blockIdx.x * 32;
    float4* Wl4 = (float4*)Wls;
    float4* Xl4 = (float4*)Xls;

    for (int i = t; i < 64 * D4; i += 256) {
        int r = i / D4, d4 = i % D4;
        Wl4[r * D4 + (d4 ^ (((r >> 4) & 3) << 2))] = ((const float4*)WT)[i];
    }
    for (int i = t; i < 32 * D4; i += 256) {
        int nd = i / D4, d4 = i % D4;
        float4 v = make_float4(0.f, 0.f, 0.f, 0.f);
        int node = node0 + nd;
        if (node < n) {
            v = ((const float4*)X)[(size_t)node * D4 + d4];
            if (RELU) {
                v.x = fmaxf(v.x, 0.f); v.y = fmaxf(v.y, 0.f);
                v.z = fmaxf(v.z, 0.f); v.w = fmaxf(v.w, 0.f);
            }
            float di = dinv[node];
            v.x *= di; v.y *= di; v.z *= di; v.w *= di;
        }
        Xl4[i] = v;
    }
    __syncthreads();

    const int wv = t >> 6, lane = t & 63;
    const int swz = ((lane >> 4) & 3) << 2;
    float acc[8];
    #pragma unroll
    for (int q = 0; q < 8; q++) acc[q] = 0.f;

    #pragma unroll 4
    for (int d4 = 0; d4 < D4; d4++) {
        float4 w = Wl4[lane * D4 + (d4 ^ swz)];
        #pragma unroll
        for (int q = 0; q < 8; q++) {
            float4 xv = Xl4[(wv * 8 + q) * D4 + d4];
            acc[q] = fmaf(xv.w, w.w, fmaf(xv.z, w.z, fmaf(xv.y, w.y, fmaf(xv.x, w.x, acc[q]))));
        }
    }
    #pragma unroll
    for (int q = 0; q < 8; q++) {
        int node = node0 + wv * 8 + q;
        if (node < n) hWs[(size_t)node * 64 + lane] = acc[q];
    }
}

// Gather: agg[c] = (sum_{in-edges} hWs[src] + hWs[c]) * dinv[c] + b.
// Wave per node; lane = (edge-slot 0..3, feat4 0..15): one dwordx4 load covers
// 4 edges per wave-instr. Cross-slot reduce via shfl_xor(16,32).
__global__ __launch_bounds__(256) void k_gather(const int* __restrict__ rowptr,
                                                const int* __restrict__ srcidx,
                                                const float* __restrict__ dinv,
                                                const float* __restrict__ b,
                                                const float* __restrict__ hWs,
                                                float* __restrict__ agg, int n) {
    const int t = threadIdx.x;
    int w = (blockIdx.x * 256 + t) >> 6;
    if (w >= n) return;
    w = __builtin_amdgcn_readfirstlane(w);
    const int lane = t & 63;
    const int f4 = lane & 15;
    const int es = lane >> 4;
    const float4* H4 = (const float4*)hWs;
    const int s = rowptr[w], e = rowptr[w + 1];
    float4 acc = make_float4(0.f, 0.f, 0.f, 0.f);
    if (es == 0) acc = H4[(size_t)w * 16 + f4];   // self loop
    for (int i = s + es; i < e; i += 4) {
        int src = srcidx[i];
        float4 v = H4[(size_t)src * 16 + f4];
        acc.x += v.x; acc.y += v.y; acc.z += v.z; acc.w += v.w;
    }
    #pragma unroll
    for (int off = 16; off < 64; off <<= 1) {
        acc.x += __shfl_xor(acc.x, off);
        acc.y += __shfl_xor(acc.y, off);
        acc.z += __shfl_xor(acc.z, off);
        acc.w += __shfl_xor(acc.w, off);
    }
    if (es == 0) {
        float di = dinv[w];
        float4 bv = ((const float4*)b)[f4];
        float4 o;
        o.x = fmaf(acc.x, di, bv.x);
        o.y = fmaf(acc.y, di, bv.y);
        o.z = fmaf(acc.z, di, bv.z);
        o.w = fmaf(acc.w, di, bv.w);
        ((float4*)agg)[(size_t)w * 16 + f4] = o;
    }
}

__device__ __forceinline__ float sigm(float x) { return 1.f / (1.f + __expf(-x)); }
__device__ __forceinline__ float tanhf_(float x) { return 1.f - 2.f / (__expf(2.f * x) + 1.f); }

// LSTM + FC. Block 512 = 8 waves; wave = 8 nodes; lane owns k = {lane, 64+lane}.
// W_ih staged per-gate (i,g,o) in XOR-swizzled LDS (128 rows x 64).
// FC reduced per node via butterfly, accumulated in tiny LDS, then stored.
__global__ __launch_bounds__(512) void k_lstm_fc(const float* __restrict__ agg,
                                                 const float* __restrict__ W_ih,
                                                 const float* __restrict__ b_ih,
                                                 const float* __restrict__ b_hh,
                                                 const float* __restrict__ W_fc,
                                                 const float* __restrict__ b_fc,
                                                 float* __restrict__ out, int n) {
    __shared__ float Wls[128 * 64];    // 32 KB (one gate at a time)
    __shared__ float hNs[64 * 64];     // 16 KB
    __shared__ float bbs[384];
    __shared__ float fca[8][8][10];
    const int t = threadIdx.x;
    const int wv = t >> 6, lane = t & 63;
    const int node0 = blockIdx.x * 64;
    float4* Wl4 = (float4*)Wls;
    float4* h4 = (float4*)hNs;
    const float4* A4 = (const float4*)agg;
    const float4* Wih4 = (const float4*)W_ih;

    for (int i = t; i < 64 * 16; i += 512) {
        int nd = i >> 4;
        float4 v = make_float4(0.f, 0.f, 0.f, 0.f);
        if (node0 + nd < n) {
            v = A4[(size_t)(node0 + nd) * 16 + (i & 15)];
            v.x = fmaxf(v.x, 0.f); v.y = fmaxf(v.y, 0.f);
            v.z = fmaxf(v.z, 0.f); v.w = fmaxf(v.w, 0.f);
        }
        h4[i] = v;
    }
    for (int i = t; i < 384; i += 512) {
        int g = i >> 7, k = i & 127;
        int grow = (g == 0) ? 0 : ((g + 1) * 128);  // gates i,g,o = rows 0,256,384
        bbs[i] = b_ih[grow + k] + b_hh[grow + k];
    }
    for (int i = t; i < 640; i += 512) ((float*)fca)[i] = 0.f;

    const int swz = ((lane >> 4) & 3) << 2;
    float ac[3][2][8];
    #pragma unroll
    for (int g = 0; g < 3; g++)
        #pragma unroll
        for (int h = 0; h < 2; h++)
            #pragma unroll
            for (int q = 0; q < 8; q++) ac[g][h][q] = 0.f;

    #pragma unroll
    for (int g = 0; g < 3; g++) {
        __syncthreads();
        const int grow0 = (g == 0) ? 0 : ((g + 1) * 128);
        for (int i = t; i < 128 * 16; i += 512) {
            int r = i >> 4, d4 = i & 15;
            Wl4[(r << 4) | (d4 ^ (((r >> 4) & 3) << 2))] = Wih4[(size_t)(grow0 + r) * 16 + d4];
        }
        __syncthreads();
        #pragma unroll 2
        for (int j = 0; j < 16; j++) {
            int js = j ^ swz;
            float4 w0 = Wl4[(lane << 4) | js];
            float4 w1 = Wl4[((64 + lane) << 4) | js];
            #pragma unroll
            for (int q = 0; q < 8; q++) {
                float4 hv = h4[((wv * 8 + q) << 4) | j];
                ac[g][0][q] = fmaf(hv.w, w0.w, fmaf(hv.z, w0.z, fmaf(hv.y, w0.y, fmaf(hv.x, w0.x, ac[g][0][q]))));
                ac[g][1][q] = fmaf(hv.w, w1.w, fmaf(hv.z, w1.z, fmaf(hv.y, w1.y, fmaf(hv.x, w1.x, ac[g][1][q]))));
            }
        }
    }

    float wfa[10], wfb[10];
    #pragma unroll
    for (int c = 0; c < 10; c++) {
        wfa[c] = W_fc[c * 128 + lane];
        wfb[c] = W_fc[c * 128 + 64 + lane];
    }
    const float bi0 = bbs[lane],      bg0 = bbs[128 + lane], bo0 = bbs[256 + lane];
    const float bi1 = bbs[64 + lane], bg1 = bbs[192 + lane], bo1 = bbs[320 + lane];

    #pragma unroll
    for (int q = 0; q < 8; q++) {
        float gi0 = ac[0][0][q] + bi0, gg0 = ac[1][0][q] + bg0, go0 = ac[2][0][q] + bo0;
        float gi1 = ac[0][1][q] + bi1, gg1 = ac[1][1][q] + bg1, go1 = ac[2][1][q] + bo1;
        float h1a = sigm(go0) * tanhf_(sigm(gi0) * tanhf_(gg0));
        float h1b = sigm(go1) * tanhf_(sigm(gi1) * tanhf_(gg1));
        float p[10];
        #pragma unroll
        for (int c = 0; c < 10; c++) p[c] = fmaf(h1b, wfb[c], h1a * wfa[c]);
        #pragma unroll
        for (int off = 1; off < 64; off <<= 1) {
            #pragma unroll
            for (int c = 0; c < 10; c++) p[c] += __shfl_xor(p[c], off);
        }
        if (lane == 0) {
            #pragma unroll
            for (int c = 0; c < 10; c++) fca[wv][q][c] += p[c];
        }
    }
    __syncthreads();
    for (int i = t; i < 640; i += 512) {
        int nd = i / 10, c = i % 10;
        int node = node0 + nd;
        if (node < n) out[(size_t)node * 10 + c] = fca[nd >> 3][nd & 7][c] + b_fc[c];
    }
}

extern "C" void kernel_launch(void* const* d_in, const int* in_sizes, int n_in,
                              void* d_out, int out_size, void* d_ws, size_t ws_size,
                              hipStream_t stream) {
    const float* x    = (const float*)d_in[0];
    const int*   ei   = (const int*)d_in[1];
    const float* W1   = (const float*)d_in[2];
    const float* b1   = (const float*)d_in[3];
    const float* W2   = (const float*)d_in[4];
    const float* b2   = (const float*)d_in[5];
    const float* W3   = (const float*)d_in[6];
    const float* b3   = (const float*)d_in[7];
    const float* W4   = (const float*)d_in[8];
    const float* b4   = (const float*)d_in[9];
    const float* W5   = (const float*)d_in[10];
    const float* b5   = (const float*)d_in[11];
    const float* W_ih = (const float*)d_in[12];
    // d_in[13] = W_hh: dead (h0 = 0)
    const float* b_ih = (const float*)d_in[14];
    const float* b_hh = (const float*)d_in[15];
    const float* W_fc = (const float*)d_in[16];
    const float* b_fc = (const float*)d_in[17];
    float* out = (float*)d_out;

    const int N = in_sizes[0] / 128;
    const int E = in_sizes[1] / 2;
    const int* row = ei;
    const int* col = ei + E;

    // workspace layout (4-byte units, each region 16B-aligned)
    size_t off = 0;
    auto alloc = [&](size_t elems) { size_t cur = off; off += (elems + 3) & ~(size_t)3; return cur; };
    int*   base_i = (int*)d_ws;
    float* base_f = (float*)d_ws;
    int*   cnt    = base_i + alloc(N);
    int*   rowptr = base_i + alloc((size_t)N + 1);
    int*   cursor = base_i + alloc(N);
    int*   srcidx = base_i + alloc(E);
    float* dinv   = base_f + alloc(N);
    float* WT     = base_f + alloc(24576);
    float* hWs    = base_f + alloc((size_t)N * 64);
    float* agg    = base_f + alloc((size_t)N * 64);
    float* WT1 = WT;
    float* WT2 = WT + 8192;
    float* WT3 = WT + 8192 + 4096;
    float* WT4 = WT + 8192 + 8192;
    float* WT5 = WT + 8192 + 12288;

    const int nbE  = (E + 255) / 256;        // 3125
    const int nbGa = (N * 64 + 255) / 256;   // 12500 (wave per node)
    const int nbGe = (N + 31) / 32;          // 1563
    const int nbL  = (N + 63) / 64;          // 782

    hipMemsetAsync(cnt, 0, sizeof(int) * N, stream);
    k_transp<<<96, 256, 0, stream>>>(W1, W2, W3, W4, W5, WT);
    k_count<<<nbE, 256, 0, stream>>>(col, cnt, E);
    k_scan<<<1, 1024, 0, stream>>>(cnt, rowptr, cursor, dinv, N);
    k_fill<<<nbE, 256, 0, stream>>>(row, col, cursor, srcidx, E);

    k_gemm2<128, false><<<nbGe, 256, 0, stream>>>(x, WT1, dinv, hWs, N);
    k_gather<<<nbGa, 256, 0, stream>>>(rowptr, srcidx, dinv, b1, hWs, agg, N);
    k_gemm2<64, true><<<nbGe, 256, 0, stream>>>(agg, WT2, dinv, hWs, N);
    k_gather<<<nbGa, 256, 0, stream>>>(rowptr, srcidx, dinv, b2, hWs, agg, N);
    k_gemm2<64, true><<<nbGe, 256, 0, stream>>>(agg, WT3, dinv, hWs, N);
    k_gather<<<nbGa, 256, 0, stream>>>(rowptr, srcidx, dinv, b3, hWs, agg, N);
    k_gemm2<64, true><<<nbGe, 256, 0, stream>>>(agg, WT4, dinv, hWs, N);
    k_gather<<<nbGa, 256, 0, stream>>>(rowptr, srcidx, dinv, b4, hWs, agg, N);
    k_gemm2<64, true><<<nbGe, 256, 0, stream>>>(agg, WT5, dinv, hWs, N);
    k_gather<<<nbGa, 256, 0, stream>>>(rowptr, srcidx, dinv, b5, hWs, agg, N);

    k_lstm_fc<<<nbL, 512, 0, stream>>>(agg, W_ih, b_ih, b_hh, W_fc, b_fc, out, N);
}

// Round 6
// 647.821 us; speedup vs baseline: 1.9040x; 1.2011x over previous
//
#include <hip/hip_runtime.h>
#include <math.h>

#define DOUT 64

// ---------------------------------------------------------------------------
// GCN(5) + LSTM(1 step) + FC head, f32, MI355X.
// Pipeline per call:
//   memset cnt; transpose W1..W5 -> WT; count indeg;
//   hierarchical scan (scanA: block sums, scanB: 1-wave scan of 49 sums,
//   scanC: per-block scan + base -> rowptr/cursor/dinv);
//   fill CSR srcidx;  5x { gemm2 (X*dinv @ W -> hWs), gather (CSR sum -> agg) };
//   lstm_fc (wave = 8 nodes, lane = k; gate-chunked W_ih in swizzled LDS).
// h0=c0=0  =>  f-gate and W_hh are dead; c1 = i*g.
// ---------------------------------------------------------------------------

__global__ __launch_bounds__(256) void k_count(const int* __restrict__ col,
                                               int* __restrict__ cnt, int e) {
    int i = blockIdx.x * 256 + threadIdx.x;
    if (i < e) atomicAdd(&cnt[col[i]], 1);
}

// ---- hierarchical exclusive scan of cnt[0..n) (replaces 153us 1-block scan).
// chunk = 1024 nodes/block (4/thread). Requires nblocks <= 64 (n <= 65536).

__global__ __launch_bounds__(256) void k_scanA(const int* __restrict__ cnt,
                                               int* __restrict__ bsum, int n) {
    __shared__ int part[256];
    const int t = threadIdx.x;
    const int base = blockIdx.x * 1024 + t * 4;
    int s = 0;
    #pragma unroll
    for (int i = 0; i < 4; i++) { int idx = base + i; if (idx < n) s += cnt[idx]; }
    part[t] = s;
    __syncthreads();
    #pragma unroll
    for (int off = 128; off > 0; off >>= 1) {
        if (t < off) part[t] += part[t + off];
        __syncthreads();
    }
    if (t == 0) bsum[blockIdx.x] = part[0];
}

__global__ __launch_bounds__(64) void k_scanB(const int* __restrict__ bsum,
                                              int* __restrict__ boff, int nb) {
    const int t = threadIdx.x;          // single wave of 64
    int val = (t < nb) ? bsum[t] : 0;
    const int own = val;
    #pragma unroll
    for (int off = 1; off < 64; off <<= 1) {
        int v = __shfl_up(val, off);
        if (t >= off) val += v;
    }
    if (t < nb) boff[t] = val - own;    // exclusive
}

__global__ __launch_bounds__(256) void k_scanC(const int* __restrict__ cnt,
                                               const int* __restrict__ boff,
                                               int* __restrict__ rowptr,
                                               int* __restrict__ cursor,
                                               float* __restrict__ dinv,
                                               int n, int e_total) {
    __shared__ int part[256];
    const int t = threadIdx.x;
    const int base = blockIdx.x * 1024 + t * 4;
    int c[4];
    int s = 0;
    #pragma unroll
    for (int i = 0; i < 4; i++) {
        int idx = base + i;
        c[i] = (idx < n) ? cnt[idx] : 0;
        s += c[i];
    }
    part[t] = s;
    __syncthreads();
    // inclusive Hillis-Steele over thread totals
    for (int off = 1; off < 256; off <<= 1) {
        int v = 0;
        if (t >= off) v = part[t - off];
        __syncthreads();
        if (t >= off) part[t] += v;
        __syncthreads();
    }
    int run = boff[blockIdx.x] + ((t > 0) ? part[t - 1] : 0);  // exclusive base
    #pragma unroll
    for (int i = 0; i < 4; i++) {
        int idx = base + i;
        if (idx < n) {
            rowptr[idx] = run;
            cursor[idx] = run;
            dinv[idx] = rsqrtf((float)(c[i] + 1));   // +1 self loop
            run += c[i];
        }
    }
    if (blockIdx.x == 0 && t == 0) rowptr[n] = e_total;
}

__global__ __launch_bounds__(256) void k_fill(const int* __restrict__ row,
                                              const int* __restrict__ col,
                                              int* __restrict__ cursor,
                                              int* __restrict__ srcidx, int e) {
    int i = blockIdx.x * 256 + threadIdx.x;
    if (i < e) {
        int p = atomicAdd(&cursor[col[i]], 1);
        srcidx[p] = row[i];
    }
}

// Transpose all 5 GCN weights: WT[j][d] = W[d][j].  W1:128x64, W2..W5:64x64.
__global__ __launch_bounds__(256) void k_transp(const float* __restrict__ W1,
                                                const float* __restrict__ W2,
                                                const float* __restrict__ W3,
                                                const float* __restrict__ W4,
                                                const float* __restrict__ W5,
                                                float* __restrict__ WT) {
    int i = blockIdx.x * 256 + threadIdx.x;
    if (i < 8192) {
        int j = i >> 7, d = i & 127;
        WT[i] = W1[d * 64 + j];
    } else if (i < 24576) {
        int q = i - 8192;
        int w = q >> 12, r = q & 4095;
        int j = r >> 6, d = r & 63;
        const float* Ws = (w == 0) ? W2 : (w == 1) ? W3 : (w == 2) ? W4 : W5;
        WT[i] = Ws[d * 64 + j];
    }
}

// GEMM: hWs[node] = (relu?(X[node]) * dinv[node]) @ W.
// Block 256 = 4 waves, 8 nodes/wave (32/block). lane = output column.
// W in LDS column-major with XOR swizzle (worst 2-way conflict = free).
template<int D, bool RELU>
__global__ __launch_bounds__(256) void k_gemm2(const float* __restrict__ X,
                                               const float* __restrict__ WT,
                                               const float* __restrict__ dinv,
                                               float* __restrict__ hWs, int n) {
    constexpr int D4 = D / 4;
    __shared__ float Wls[64 * D];
    __shared__ float Xls[32 * D];
    const int t = threadIdx.x;
    const int node0 = blockIdx.x * 32;
    float4* Wl4 = (float4*)Wls;
    float4* Xl4 = (float4*)Xls;

    for (int i = t; i < 64 * D4; i += 256) {
        int r = i / D4, d4 = i % D4;
        Wl4[r * D4 + (d4 ^ (((r >> 4) & 3) << 2))] = ((const float4*)WT)[i];
    }
    for (int i = t; i < 32 * D4; i += 256) {
        int nd = i / D4, d4 = i % D4;
        float4 v = make_float4(0.f, 0.f, 0.f, 0.f);
        int node = node0 + nd;
        if (node < n) {
            v = ((const float4*)X)[(size_t)node * D4 + d4];
            if (RELU) {
                v.x = fmaxf(v.x, 0.f); v.y = fmaxf(v.y, 0.f);
                v.z = fmaxf(v.z, 0.f); v.w = fmaxf(v.w, 0.f);
            }
            float di = dinv[node];
            v.x *= di; v.y *= di; v.z *= di; v.w *= di;
        }
        Xl4[i] = v;
    }
    __syncthreads();

    const int wv = t >> 6, lane = t & 63;
    const int swz = ((lane >> 4) & 3) << 2;
    float acc[8];
    #pragma unroll
    for (int q = 0; q < 8; q++) acc[q] = 0.f;

    #pragma unroll 4
    for (int d4 = 0; d4 < D4; d4++) {
        float4 w = Wl4[lane * D4 + (d4 ^ swz)];
        #pragma unroll
        for (int q = 0; q < 8; q++) {
            float4 xv = Xl4[(wv * 8 + q) * D4 + d4];
            acc[q] = fmaf(xv.w, w.w, fmaf(xv.z, w.z, fmaf(xv.y, w.y, fmaf(xv.x, w.x, acc[q]))));
        }
    }
    #pragma unroll
    for (int q = 0; q < 8; q++) {
        int node = node0 + wv * 8 + q;
        if (node < n) hWs[(size_t)node * 64 + lane] = acc[q];
    }
}

// Gather: agg[c] = (sum_{in-edges} hWs[src] + hWs[c]) * dinv[c] + b.
// Wave per node; lane = (edge-slot 0..3, feat4 0..15): one dwordx4 load covers
// 4 edges per wave-instr. Cross-slot reduce via shfl_xor(16,32).
__global__ __launch_bounds__(256) void k_gather(const int* __restrict__ rowptr,
                                                const int* __restrict__ srcidx,
                                                const float* __restrict__ dinv,
                                                const float* __restrict__ b,
                                                const float* __restrict__ hWs,
                                                float* __restrict__ agg, int n) {
    const int t = threadIdx.x;
    int w = (blockIdx.x * 256 + t) >> 6;
    if (w >= n) return;
    w = __builtin_amdgcn_readfirstlane(w);
    const int lane = t & 63;
    const int f4 = lane & 15;
    const int es = lane >> 4;
    const float4* H4 = (const float4*)hWs;
    const int s = rowptr[w], e = rowptr[w + 1];
    float4 acc = make_float4(0.f, 0.f, 0.f, 0.f);
    if (es == 0) acc = H4[(size_t)w * 16 + f4];   // self loop
    for (int i = s + es; i < e; i += 4) {
        int src = srcidx[i];
        float4 v = H4[(size_t)src * 16 + f4];
        acc.x += v.x; acc.y += v.y; acc.z += v.z; acc.w += v.w;
    }
    #pragma unroll
    for (int off = 16; off < 64; off <<= 1) {
        acc.x += __shfl_xor(acc.x, off);
        acc.y += __shfl_xor(acc.y, off);
        acc.z += __shfl_xor(acc.z, off);
        acc.w += __shfl_xor(acc.w, off);
    }
    if (es == 0) {
        float di = dinv[w];
        float4 bv = ((const float4*)b)[f4];
        float4 o;
        o.x = fmaf(acc.x, di, bv.x);
        o.y = fmaf(acc.y, di, bv.y);
        o.z = fmaf(acc.z, di, bv.z);
        o.w = fmaf(acc.w, di, bv.w);
        ((float4*)agg)[(size_t)w * 16 + f4] = o;
    }
}

__device__ __forceinline__ float sigm(float x) { return 1.f / (1.f + __expf(-x)); }
__device__ __forceinline__ float tanhf_(float x) { return 1.f - 2.f / (__expf(2.f * x) + 1.f); }

// LSTM + FC. Block 512 = 8 waves; wave = 8 nodes; lane owns k = {lane, 64+lane}.
// W_ih staged per-gate (i,g,o) in XOR-swizzled LDS (128 rows x 64).
// FC reduced per node via butterfly, accumulated in tiny LDS, then stored.
__global__ __launch_bounds__(512) void k_lstm_fc(const float* __restrict__ agg,
                                                 const float* __restrict__ W_ih,
                                                 const float* __restrict__ b_ih,
                                                 const float* __restrict__ b_hh,
                                                 const float* __restrict__ W_fc,
                                                 const float* __restrict__ b_fc,
                                                 float* __restrict__ out, int n) {
    __shared__ float Wls[128 * 64];    // 32 KB (one gate at a time)
    __shared__ float hNs[64 * 64];     // 16 KB
    __shared__ float bbs[384];
    __shared__ float fca[8][8][10];
    const int t = threadIdx.x;
    const int wv = t >> 6, lane = t & 63;
    const int node0 = blockIdx.x * 64;
    float4* Wl4 = (float4*)Wls;
    float4* h4 = (float4*)hNs;
    const float4* A4 = (const float4*)agg;
    const float4* Wih4 = (const float4*)W_ih;

    for (int i = t; i < 64 * 16; i += 512) {
        int nd = i >> 4;
        float4 v = make_float4(0.f, 0.f, 0.f, 0.f);
        if (node0 + nd < n) {
            v = A4[(size_t)(node0 + nd) * 16 + (i & 15)];
            v.x = fmaxf(v.x, 0.f); v.y = fmaxf(v.y, 0.f);
            v.z = fmaxf(v.z, 0.f); v.w = fmaxf(v.w, 0.f);
        }
        h4[i] = v;
    }
    for (int i = t; i < 384; i += 512) {
        int g = i >> 7, k = i & 127;
        int grow = (g == 0) ? 0 : ((g + 1) * 128);  // gates i,g,o = rows 0,256,384
        bbs[i] = b_ih[grow + k] + b_hh[grow + k];
    }
    for (int i = t; i < 640; i += 512) ((float*)fca)[i] = 0.f;

    const int swz = ((lane >> 4) & 3) << 2;
    float ac[3][2][8];
    #pragma unroll
    for (int g = 0; g < 3; g++)
        #pragma unroll
        for (int h = 0; h < 2; h++)
            #pragma unroll
            for (int q = 0; q < 8; q++) ac[g][h][q] = 0.f;

    #pragma unroll
    for (int g = 0; g < 3; g++) {
        __syncthreads();
        const int grow0 = (g == 0) ? 0 : ((g + 1) * 128);
        for (int i = t; i < 128 * 16; i += 512) {
            int r = i >> 4, d4 = i & 15;
            Wl4[(r << 4) | (d4 ^ (((r >> 4) & 3) << 2))] = Wih4[(size_t)(grow0 + r) * 16 + d4];
        }
        __syncthreads();
        #pragma unroll 2
        for (int j = 0; j < 16; j++) {
            int js = j ^ swz;
            float4 w0 = Wl4[(lane << 4) | js];
            float4 w1 = Wl4[((64 + lane) << 4) | js];
            #pragma unroll
            for (int q = 0; q < 8; q++) {
                float4 hv = h4[((wv * 8 + q) << 4) | j];
                ac[g][0][q] = fmaf(hv.w, w0.w, fmaf(hv.z, w0.z, fmaf(hv.y, w0.y, fmaf(hv.x, w0.x, ac[g][0][q]))));
                ac[g][1][q] = fmaf(hv.w, w1.w, fmaf(hv.z, w1.z, fmaf(hv.y, w1.y, fmaf(hv.x, w1.x, ac[g][1][q]))));
            }
        }
    }

    float wfa[10], wfb[10];
    #pragma unroll
    for (int c = 0; c < 10; c++) {
        wfa[c] = W_fc[c * 128 + lane];
        wfb[c] = W_fc[c * 128 + 64 + lane];
    }
    const float bi0 = bbs[lane],      bg0 = bbs[128 + lane], bo0 = bbs[256 + lane];
    const float bi1 = bbs[64 + lane], bg1 = bbs[192 + lane], bo1 = bbs[320 + lane];

    #pragma unroll
    for (int q = 0; q < 8; q++) {
        float gi0 = ac[0][0][q] + bi0, gg0 = ac[1][0][q] + bg0, go0 = ac[2][0][q] + bo0;
        float gi1 = ac[0][1][q] + bi1, gg1 = ac[1][1][q] + bg1, go1 = ac[2][1][q] + bo1;
        float h1a = sigm(go0) * tanhf_(sigm(gi0) * tanhf_(gg0));
        float h1b = sigm(go1) * tanhf_(sigm(gi1) * tanhf_(gg1));
        float p[10];
        #pragma unroll
        for (int c = 0; c < 10; c++) p[c] = fmaf(h1b, wfb[c], h1a * wfa[c]);
        #pragma unroll
        for (int off = 1; off < 64; off <<= 1) {
            #pragma unroll
            for (int c = 0; c < 10; c++) p[c] += __shfl_xor(p[c], off);
        }
        if (lane == 0) {
            #pragma unroll
            for (int c = 0; c < 10; c++) fca[wv][q][c] += p[c];
        }
    }
    __syncthreads();
    for (int i = t; i < 640; i += 512) {
        int nd = i / 10, c = i % 10;
        int node = node0 + nd;
        if (node < n) out[(size_t)node * 10 + c] = fca[nd >> 3][nd & 7][c] + b_fc[c];
    }
}

extern "C" void kernel_launch(void* const* d_in, const int* in_sizes, int n_in,
                              void* d_out, int out_size, void* d_ws, size_t ws_size,
                              hipStream_t stream) {
    const float* x    = (const float*)d_in[0];
    const int*   ei   = (const int*)d_in[1];
    const float* W1   = (const float*)d_in[2];
    const float* b1   = (const float*)d_in[3];
    const float* W2   = (const float*)d_in[4];
    const float* b2   = (const float*)d_in[5];
    const float* W3   = (const float*)d_in[6];
    const float* b3   = (const float*)d_in[7];
    const float* W4   = (const float*)d_in[8];
    const float* b4   = (const float*)d_in[9];
    const float* W5   = (const float*)d_in[10];
    const float* b5   = (const float*)d_in[11];
    const float* W_ih = (const float*)d_in[12];
    // d_in[13] = W_hh: dead (h0 = 0)
    const float* b_ih = (const float*)d_in[14];
    const float* b_hh = (const float*)d_in[15];
    const float* W_fc = (const float*)d_in[16];
    const float* b_fc = (const float*)d_in[17];
    float* out = (float*)d_out;

    const int N = in_sizes[0] / 128;
    const int E = in_sizes[1] / 2;
    const int* row = ei;
    const int* col = ei + E;

    // workspace layout (4-byte units, each region 16B-aligned)
    size_t off = 0;
    auto alloc = [&](size_t elems) { size_t cur = off; off += (elems + 3) & ~(size_t)3; return cur; };
    int*   base_i = (int*)d_ws;
    float* base_f = (float*)d_ws;
    int*   cnt    = base_i + alloc(N);
    int*   rowptr = base_i + alloc((size_t)N + 1);
    int*   cursor = base_i + alloc(N);
    int*   srcidx = base_i + alloc(E);
    int*   bsum   = base_i + alloc(64);
    int*   boff   = base_i + alloc(64);
    float* dinv   = base_f + alloc(N);
    float* WT     = base_f + alloc(24576);
    float* hWs    = base_f + alloc((size_t)N * 64);
    float* agg    = base_f + alloc((size_t)N * 64);
    float* WT1 = WT;
    float* WT2 = WT + 8192;
    float* WT3 = WT + 8192 + 4096;
    float* WT4 = WT + 8192 + 8192;
    float* WT5 = WT + 8192 + 12288;

    const int nbE  = (E + 255) / 256;        // 3125
    const int nbGa = (N * 64 + 255) / 256;   // 12500 (wave per node)
    const int nbGe = (N + 31) / 32;          // 1563
    const int nbL  = (N + 63) / 64;          // 782
    const int nbS  = (N + 1023) / 1024;      // 49 (must be <= 64)

    hipMemsetAsync(cnt, 0, sizeof(int) * N, stream);
    k_transp<<<96, 256, 0, stream>>>(W1, W2, W3, W4, W5, WT);
    k_count<<<nbE, 256, 0, stream>>>(col, cnt, E);
    k_scanA<<<nbS, 256, 0, stream>>>(cnt, bsum, N);
    k_scanB<<<1, 64, 0, stream>>>(bsum, boff, nbS);
    k_scanC<<<nbS, 256, 0, stream>>>(cnt, boff, rowptr, cursor, dinv, N, E);
    k_fill<<<nbE, 256, 0, stream>>>(row, col, cursor, srcidx, E);

    k_gemm2<128, false><<<nbGe, 256, 0, stream>>>(x, WT1, dinv, hWs, N);
    k_gather<<<nbGa, 256, 0, stream>>>(rowptr, srcidx, dinv, b1, hWs, agg, N);
    k_gemm2<64, true><<<nbGe, 256, 0, stream>>>(agg, WT2, dinv, hWs, N);
    k_gather<<<nbGa, 256, 0, stream>>>(rowptr, srcidx, dinv, b2, hWs, agg, N);
    k_gemm2<64, true><<<nbGe, 256, 0, stream>>>(agg, WT3, dinv, hWs, N);
    k_gather<<<nbGa, 256, 0, stream>>>(rowptr, srcidx, dinv, b3, hWs, agg, N);
    k_gemm2<64, true><<<nbGe, 256, 0, stream>>>(agg, WT4, dinv, hWs, N);
    k_gather<<<nbGa, 256, 0, stream>>>(rowptr, srcidx, dinv, b4, hWs, agg, N);
    k_gemm2<64, true><<<nbGe, 256, 0, stream>>>(agg, WT5, dinv, hWs, N);
    k_gather<<<nbGa, 256, 0, stream>>>(rowptr, srcidx, dinv, b5, hWs, agg, N);

    k_lstm_fc<<<nbL, 512, 0, stream>>>(agg, W_ih, b_ih, b_hh, W_fc, b_fc, out, N);
}

// Round 7
// 592.164 us; speedup vs baseline: 2.0829x; 1.0940x over previous
//
#include <hip/hip_runtime.h>
#include <math.h>

#define DOUT 64

// ---------------------------------------------------------------------------
// GCN(5) + LSTM(1 step) + FC head, f32, MI355X.
// h0=c0=0  =>  f-gate and W_hh are dead; c1 = i*g.
// ---------------------------------------------------------------------------

__global__ __launch_bounds__(256) void k_count(const int* __restrict__ col,
                                               int* __restrict__ cnt, int e) {
    int i = blockIdx.x * 256 + threadIdx.x;
    if (i < e) atomicAdd(&cnt[col[i]], 1);
}

// ---- hierarchical exclusive scan of cnt[0..n): 1024 nodes/block, <=64 blocks.

__global__ __launch_bounds__(256) void k_scanA(const int* __restrict__ cnt,
                                               int* __restrict__ bsum, int n) {
    __shared__ int part[256];
    const int t = threadIdx.x;
    const int base = blockIdx.x * 1024 + t * 4;
    int s = 0;
    #pragma unroll
    for (int i = 0; i < 4; i++) { int idx = base + i; if (idx < n) s += cnt[idx]; }
    part[t] = s;
    __syncthreads();
    #pragma unroll
    for (int off = 128; off > 0; off >>= 1) {
        if (t < off) part[t] += part[t + off];
        __syncthreads();
    }
    if (t == 0) bsum[blockIdx.x] = part[0];
}

__global__ __launch_bounds__(64) void k_scanB(const int* __restrict__ bsum,
                                              int* __restrict__ boff, int nb) {
    const int t = threadIdx.x;          // single wave of 64
    int val = (t < nb) ? bsum[t] : 0;
    const int own = val;
    #pragma unroll
    for (int off = 1; off < 64; off <<= 1) {
        int v = __shfl_up(val, off);
        if (t >= off) val += v;
    }
    if (t < nb) boff[t] = val - own;    // exclusive
}

__global__ __launch_bounds__(256) void k_scanC(const int* __restrict__ cnt,
                                               const int* __restrict__ boff,
                                               int* __restrict__ rowptr,
                                               int* __restrict__ cursor,
                                               float* __restrict__ dinv,
                                               int n, int e_total) {
    __shared__ int part[256];
    const int t = threadIdx.x;
    const int base = blockIdx.x * 1024 + t * 4;
    int c[4];
    int s = 0;
    #pragma unroll
    for (int i = 0; i < 4; i++) {
        int idx = base + i;
        c[i] = (idx < n) ? cnt[idx] : 0;
        s += c[i];
    }
    part[t] = s;
    __syncthreads();
    for (int off = 1; off < 256; off <<= 1) {
        int v = 0;
        if (t >= off) v = part[t - off];
        __syncthreads();
        if (t >= off) part[t] += v;
        __syncthreads();
    }
    int run = boff[blockIdx.x] + ((t > 0) ? part[t - 1] : 0);  // exclusive base
    #pragma unroll
    for (int i = 0; i < 4; i++) {
        int idx = base + i;
        if (idx < n) {
            rowptr[idx] = run;
            cursor[idx] = run;
            dinv[idx] = rsqrtf((float)(c[i] + 1));   // +1 self loop
            run += c[i];
        }
    }
    if (blockIdx.x == 0 && t == 0) rowptr[n] = e_total;
}

__global__ __launch_bounds__(256) void k_fill(const int* __restrict__ row,
                                              const int* __restrict__ col,
                                              int* __restrict__ cursor,
                                              int* __restrict__ srcidx, int e) {
    int i = blockIdx.x * 256 + threadIdx.x;
    if (i < e) {
        int p = atomicAdd(&cursor[col[i]], 1);
        srcidx[p] = row[i];
    }
}

// Transpose all 5 GCN weights: WT[j][d] = W[d][j].  W1:128x64, W2..W5:64x64.
__global__ __launch_bounds__(256) void k_transp(const float* __restrict__ W1,
                                                const float* __restrict__ W2,
                                                const float* __restrict__ W3,
                                                const float* __restrict__ W4,
                                                const float* __restrict__ W5,
                                                float* __restrict__ WT) {
    int i = blockIdx.x * 256 + threadIdx.x;
    if (i < 8192) {
        int j = i >> 7, d = i & 127;
        WT[i] = W1[d * 64 + j];
    } else if (i < 24576) {
        int q = i - 8192;
        int w = q >> 12, r = q & 4095;
        int j = r >> 6, d = r & 63;
        const float* Ws = (w == 0) ? W2 : (w == 1) ? W3 : (w == 2) ? W4 : W5;
        WT[i] = Ws[d * 64 + j];
    }
}

// GEMM: hWs[node] = (relu?(X[node]) * dinv[node]) @ W.
template<int D, bool RELU>
__global__ __launch_bounds__(256) void k_gemm2(const float* __restrict__ X,
                                               const float* __restrict__ WT,
                                               const float* __restrict__ dinv,
                                               float* __restrict__ hWs, int n) {
    constexpr int D4 = D / 4;
    __shared__ float Wls[64 * D];
    __shared__ float Xls[32 * D];
    const int t = threadIdx.x;
    const int node0 = blockIdx.x * 32;
    float4* Wl4 = (float4*)Wls;
    float4* Xl4 = (float4*)Xls;

    for (int i = t; i < 64 * D4; i += 256) {
        int r = i / D4, d4 = i % D4;
        Wl4[r * D4 + (d4 ^ (((r >> 4) & 3) << 2))] = ((const float4*)WT)[i];
    }
    for (int i = t; i < 32 * D4; i += 256) {
        int nd = i / D4, d4 = i % D4;
        float4 v = make_float4(0.f, 0.f, 0.f, 0.f);
        int node = node0 + nd;
        if (node < n) {
            v = ((const float4*)X)[(size_t)node * D4 + d4];
            if (RELU) {
                v.x = fmaxf(v.x, 0.f); v.y = fmaxf(v.y, 0.f);
                v.z = fmaxf(v.z, 0.f); v.w = fmaxf(v.w, 0.f);
            }
            float di = dinv[node];
            v.x *= di; v.y *= di; v.z *= di; v.w *= di;
        }
        Xl4[i] = v;
    }
    __syncthreads();

    const int wv = t >> 6, lane = t & 63;
    const int swz = ((lane >> 4) & 3) << 2;
    float acc[8];
    #pragma unroll
    for (int q = 0; q < 8; q++) acc[q] = 0.f;

    #pragma unroll 4
    for (int d4 = 0; d4 < D4; d4++) {
        float4 w = Wl4[lane * D4 + (d4 ^ swz)];
        #pragma unroll
        for (int q = 0; q < 8; q++) {
            float4 xv = Xl4[(wv * 8 + q) * D4 + d4];
            acc[q] = fmaf(xv.w, w.w, fmaf(xv.z, w.z, fmaf(xv.y, w.y, fmaf(xv.x, w.x, acc[q]))));
        }
    }
    #pragma unroll
    for (int q = 0; q < 8; q++) {
        int node = node0 + wv * 8 + q;
        if (node < n) hWs[(size_t)node * 64 + lane] = acc[q];
    }
}

// Gather: agg[c] = (sum_{in-edges} hWs[src] + hWs[c]) * dinv[c] + b.
__global__ __launch_bounds__(256) void k_gather(const int* __restrict__ rowptr,
                                                const int* __restrict__ srcidx,
                                                const float* __restrict__ dinv,
                                                const float* __restrict__ b,
                                                const float* __restrict__ hWs,
                                                float* __restrict__ agg, int n) {
    const int t = threadIdx.x;
    int w = (blockIdx.x * 256 + t) >> 6;
    if (w >= n) return;
    w = __builtin_amdgcn_readfirstlane(w);
    const int lane = t & 63;
    const int f4 = lane & 15;
    const int es = lane >> 4;
    const float4* H4 = (const float4*)hWs;
    const int s = rowptr[w], e = rowptr[w + 1];
    float4 acc = make_float4(0.f, 0.f, 0.f, 0.f);
    if (es == 0) acc = H4[(size_t)w * 16 + f4];   // self loop
    for (int i = s + es; i < e; i += 4) {
        int src = srcidx[i];
        float4 v = H4[(size_t)src * 16 + f4];
        acc.x += v.x; acc.y += v.y; acc.z += v.z; acc.w += v.w;
    }
    #pragma unroll
    for (int off = 16; off < 64; off <<= 1) {
        acc.x += __shfl_xor(acc.x, off);
        acc.y += __shfl_xor(acc.y, off);
        acc.z += __shfl_xor(acc.z, off);
        acc.w += __shfl_xor(acc.w, off);
    }
    if (es == 0) {
        float di = dinv[w];
        float4 bv = ((const float4*)b)[f4];
        float4 o;
        o.x = fmaf(acc.x, di, bv.x);
        o.y = fmaf(acc.y, di, bv.y);
        o.z = fmaf(acc.z, di, bv.z);
        o.w = fmaf(acc.w, di, bv.w);
        ((float4*)agg)[(size_t)w * 16 + f4] = o;
    }
}

__device__ __forceinline__ float sigm(float x) { return 1.f / (1.f + __expf(-x)); }
__device__ __forceinline__ float tanhf_(float x) { return 1.f - 2.f / (__expf(2.f * x) + 1.f); }

// LSTM + FC, v2. Block 256 = 4 waves, 32 nodes (8/wave); lane owns k={lane,64+lane}.
// LDS exactly 40960 B -> 4 blocks/CU. Gate weights in 8-way-floor XOR-swizzled
// LDS (r&7). FC via h1->LDS (132-stride pad) + 320 broadcast dot products
// (replaces the 480-bpermute/thread butterfly). Biases in registers.
__global__ __launch_bounds__(256) void k_lstm_fc(const float* __restrict__ agg,
                                                 const float* __restrict__ W_ih,
                                                 const float* __restrict__ b_ih,
                                                 const float* __restrict__ b_hh,
                                                 const float* __restrict__ W_fc,
                                                 const float* __restrict__ b_fc,
                                                 float* __restrict__ out, int n) {
    __shared__ float smem[10240];          // 40 KB exactly
    float4* Wl4 = (float4*)smem;           // phase1: [128 r][16 f4] swizzled (32 KB)
    float4* hN4 = (float4*)(smem + 8192);  // phase1: [32 nd][16 f4] (8 KB)
    // phase2 (after sync): h1s = smem[0..4223] ([32 nd][132 pad]), wfcs = smem[4224..5503]
    const int t = threadIdx.x;
    const int wv = t >> 6, lane = t & 63;
    const int node0 = blockIdx.x * 32;
    const float4* A4 = (const float4*)agg;
    const float4* Wih4 = (const float4*)W_ih;

    // combined biases (gates i,g,o = W_ih rows 0,256,384; k = lane, 64+lane)
    const float bi0 = b_ih[lane]       + b_hh[lane];
    const float bi1 = b_ih[64 + lane]  + b_hh[64 + lane];
    const float bg0 = b_ih[256 + lane] + b_hh[256 + lane];
    const float bg1 = b_ih[320 + lane] + b_hh[320 + lane];
    const float bo0 = b_ih[384 + lane] + b_hh[384 + lane];
    const float bo1 = b_ih[448 + lane] + b_hh[448 + lane];

    // stage node features (relu of agg)
    for (int i = t; i < 512; i += 256) {
        int nd = i >> 4;
        float4 v = make_float4(0.f, 0.f, 0.f, 0.f);
        if (node0 + nd < n) {
            v = A4[(size_t)(node0 + nd) * 16 + (i & 15)];
            v.x = fmaxf(v.x, 0.f); v.y = fmaxf(v.y, 0.f);
            v.z = fmaxf(v.z, 0.f); v.w = fmaxf(v.w, 0.f);
        }
        hN4[i] = v;
    }

    float ac[3][2][8];
    #pragma unroll
    for (int g = 0; g < 3; g++)
        #pragma unroll
        for (int h = 0; h < 2; h++)
            #pragma unroll
            for (int q = 0; q < 8; q++) ac[g][h][q] = 0.f;

    const int sw = lane & 7;
    #pragma unroll
    for (int g = 0; g < 3; g++) {
        __syncthreads();
        const int grow0 = (g == 0) ? 0 : ((g + 1) * 128);
        for (int i = t; i < 2048; i += 256) {
            int r = i >> 4, d4 = i & 15;
            Wl4[(r << 4) | (d4 ^ (r & 7))] = Wih4[(size_t)(grow0 + r) * 16 + d4];
        }
        __syncthreads();
        #pragma unroll 2
        for (int j = 0; j < 16; j++) {
            int js = j ^ sw;
            float4 w0 = Wl4[(lane << 4) | js];
            float4 w1 = Wl4[((64 + lane) << 4) | js];
            #pragma unroll
            for (int q = 0; q < 8; q++) {
                float4 hv = hN4[((wv * 8 + q) << 4) | j];
                ac[g][0][q] = fmaf(hv.w, w0.w, fmaf(hv.z, w0.z, fmaf(hv.y, w0.y, fmaf(hv.x, w0.x, ac[g][0][q]))));
                ac[g][1][q] = fmaf(hv.w, w1.w, fmaf(hv.z, w1.z, fmaf(hv.y, w1.y, fmaf(hv.x, w1.x, ac[g][1][q]))));
            }
        }
    }

    __syncthreads();   // gate reads done; smem free for h1s / wfcs

    #pragma unroll
    for (int q = 0; q < 8; q++) {
        int nd = wv * 8 + q;
        float gi0 = ac[0][0][q] + bi0, gg0 = ac[1][0][q] + bg0, go0 = ac[2][0][q] + bo0;
        float gi1 = ac[0][1][q] + bi1, gg1 = ac[1][1][q] + bg1, go1 = ac[2][1][q] + bo1;
        float h1a = sigm(go0) * tanhf_(sigm(gi0) * tanhf_(gg0));
        float h1b = sigm(go1) * tanhf_(sigm(gi1) * tanhf_(gg1));
        smem[nd * 132 + lane]      = h1a;   // k = lane
        smem[nd * 132 + 64 + lane] = h1b;   // k = 64+lane
    }
    float* wfcs = smem + 4224;
    for (int i = t; i < 1280; i += 256) wfcs[i] = W_fc[i];
    __syncthreads();

    // FC: 320 outputs (32 nodes x 10 classes); h1s rows padded to 132 words
    // (quad = (nd + k4) mod 8 -> 8-way b128 floor); W_fc rows broadcast.
    for (int oc = t; oc < 320; oc += 256) {
        int nd = oc & 31, c = oc >> 5;
        const float4* hrow = (const float4*)&smem[nd * 132];
        const float4* wrow = (const float4*)&wfcs[c * 128];
        float s = 0.f;
        #pragma unroll 8
        for (int k4 = 0; k4 < 32; k4++) {
            float4 h = hrow[k4], w = wrow[k4];
            s = fmaf(h.w, w.w, fmaf(h.z, w.z, fmaf(h.y, w.y, fmaf(h.x, w.x, s))));
        }
        int node = node0 + nd;
        if (node < n) out[(size_t)node * 10 + c] = s + b_fc[c];
    }
}

extern "C" void kernel_launch(void* const* d_in, const int* in_sizes, int n_in,
                              void* d_out, int out_size, void* d_ws, size_t ws_size,
                              hipStream_t stream) {
    const float* x    = (const float*)d_in[0];
    const int*   ei   = (const int*)d_in[1];
    const float* W1   = (const float*)d_in[2];
    const float* b1   = (const float*)d_in[3];
    const float* W2   = (const float*)d_in[4];
    const float* b2   = (const float*)d_in[5];
    const float* W3   = (const float*)d_in[6];
    const float* b3   = (const float*)d_in[7];
    const float* W4   = (const float*)d_in[8];
    const float* b4   = (const float*)d_in[9];
    const float* W5   = (const float*)d_in[10];
    const float* b5   = (const float*)d_in[11];
    const float* W_ih = (const float*)d_in[12];
    // d_in[13] = W_hh: dead (h0 = 0)
    const float* b_ih = (const float*)d_in[14];
    const float* b_hh = (const float*)d_in[15];
    const float* W_fc = (const float*)d_in[16];
    const float* b_fc = (const float*)d_in[17];
    float* out = (float*)d_out;

    const int N = in_sizes[0] / 128;
    const int E = in_sizes[1] / 2;
    const int* row = ei;
    const int* col = ei + E;

    // workspace layout (4-byte units, each region 16B-aligned)
    size_t off = 0;
    auto alloc = [&](size_t elems) { size_t cur = off; off += (elems + 3) & ~(size_t)3; return cur; };
    int*   base_i = (int*)d_ws;
    float* base_f = (float*)d_ws;
    int*   cnt    = base_i + alloc(N);
    int*   rowptr = base_i + alloc((size_t)N + 1);
    int*   cursor = base_i + alloc(N);
    int*   srcidx = base_i + alloc(E);
    int*   bsum   = base_i + alloc(64);
    int*   boff   = base_i + alloc(64);
    float* dinv   = base_f + alloc(N);
    float* WT     = base_f + alloc(24576);
    float* hWs    = base_f + alloc((size_t)N * 64);
    float* agg    = base_f + alloc((size_t)N * 64);
    float* WT1 = WT;
    float* WT2 = WT + 8192;
    float* WT3 = WT + 8192 + 4096;
    float* WT4 = WT + 8192 + 8192;
    float* WT5 = WT + 8192 + 12288;

    const int nbE  = (E + 255) / 256;        // 3125
    const int nbGa = (N * 64 + 255) / 256;   // 12500 (wave per node)
    const int nbGe = (N + 31) / 32;          // 1563
    const int nbL  = (N + 31) / 32;          // 1563 (lstm v2: 32 nodes/block)
    const int nbS  = (N + 1023) / 1024;      // 49 (must be <= 64)

    hipMemsetAsync(cnt, 0, sizeof(int) * N, stream);
    k_transp<<<96, 256, 0, stream>>>(W1, W2, W3, W4, W5, WT);
    k_count<<<nbE, 256, 0, stream>>>(col, cnt, E);
    k_scanA<<<nbS, 256, 0, stream>>>(cnt, bsum, N);
    k_scanB<<<1, 64, 0, stream>>>(bsum, boff, nbS);
    k_scanC<<<nbS, 256, 0, stream>>>(cnt, boff, rowptr, cursor, dinv, N, E);
    k_fill<<<nbE, 256, 0, stream>>>(row, col, cursor, srcidx, E);

    k_gemm2<128, false><<<nbGe, 256, 0, stream>>>(x, WT1, dinv, hWs, N);
    k_gather<<<nbGa, 256, 0, stream>>>(rowptr, srcidx, dinv, b1, hWs, agg, N);
    k_gemm2<64, true><<<nbGe, 256, 0, stream>>>(agg, WT2, dinv, hWs, N);
    k_gather<<<nbGa, 256, 0, stream>>>(rowptr, srcidx, dinv, b2, hWs, agg, N);
    k_gemm2<64, true><<<nbGe, 256, 0, stream>>>(agg, WT3, dinv, hWs, N);
    k_gather<<<nbGa, 256, 0, stream>>>(rowptr, srcidx, dinv, b3, hWs, agg, N);
    k_gemm2<64, true><<<nbGe, 256, 0, stream>>>(agg, WT4, dinv, hWs, N);
    k_gather<<<nbGa, 256, 0, stream>>>(rowptr, srcidx, dinv, b4, hWs, agg, N);
    k_gemm2<64, true><<<nbGe, 256, 0, stream>>>(agg, WT5, dinv, hWs, N);
    k_gather<<<nbGa, 256, 0, stream>>>(rowptr, srcidx, dinv, b5, hWs, agg, N);

    k_lstm_fc<<<nbL, 256, 0, stream>>>(agg, W_ih, b_ih, b_hh, W_fc, b_fc, out, N);
}

// Round 10
// 559.326 us; speedup vs baseline: 2.2052x; 1.0587x over previous
//
#include <hip/hip_runtime.h>
#include <math.h>

#define DOUT 64

// ---------------------------------------------------------------------------
// GCN(5) + LSTM(1 step) + FC head, f32, MI355X.
// h0=c0=0  =>  f-gate and W_hh are dead; c1 = i*g.
// ---------------------------------------------------------------------------

__global__ __launch_bounds__(256) void k_count(const int* __restrict__ col,
                                               int* __restrict__ cnt, int e) {
    int i = blockIdx.x * 256 + threadIdx.x;
    if (i < e) atomicAdd(&cnt[col[i]], 1);
}

// ---- hierarchical exclusive scan of cnt[0..n): 1024 nodes/block, <=64 blocks.

__global__ __launch_bounds__(256) void k_scanA(const int* __restrict__ cnt,
                                               int* __restrict__ bsum, int n) {
    __shared__ int part[256];
    const int t = threadIdx.x;
    const int base = blockIdx.x * 1024 + t * 4;
    int s = 0;
    #pragma unroll
    for (int i = 0; i < 4; i++) { int idx = base + i; if (idx < n) s += cnt[idx]; }
    part[t] = s;
    __syncthreads();
    #pragma unroll
    for (int off = 128; off > 0; off >>= 1) {
        if (t < off) part[t] += part[t + off];
        __syncthreads();
    }
    if (t == 0) bsum[blockIdx.x] = part[0];
}

__global__ __launch_bounds__(64) void k_scanB(const int* __restrict__ bsum,
                                              int* __restrict__ boff, int nb) {
    const int t = threadIdx.x;          // single wave of 64
    int val = (t < nb) ? bsum[t] : 0;
    const int own = val;
    #pragma unroll
    for (int off = 1; off < 64; off <<= 1) {
        int v = __shfl_up(val, off);
        if (t >= off) val += v;
    }
    if (t < nb) boff[t] = val - own;    // exclusive
}

__global__ __launch_bounds__(256) void k_scanC(const int* __restrict__ cnt,
                                               const int* __restrict__ boff,
                                               int* __restrict__ rowptr,
                                               int* __restrict__ cursor,
                                               float* __restrict__ dinv,
                                               int n, int e_total) {
    __shared__ int part[256];
    const int t = threadIdx.x;
    const int base = blockIdx.x * 1024 + t * 4;
    int c[4];
    int s = 0;
    #pragma unroll
    for (int i = 0; i < 4; i++) {
        int idx = base + i;
        c[i] = (idx < n) ? cnt[idx] : 0;
        s += c[i];
    }
    part[t] = s;
    __syncthreads();
    for (int off = 1; off < 256; off <<= 1) {
        int v = 0;
        if (t >= off) v = part[t - off];
        __syncthreads();
        if (t >= off) part[t] += v;
        __syncthreads();
    }
    int run = boff[blockIdx.x] + ((t > 0) ? part[t - 1] : 0);  // exclusive base
    #pragma unroll
    for (int i = 0; i < 4; i++) {
        int idx = base + i;
        if (idx < n) {
            rowptr[idx] = run;
            cursor[idx] = run;
            dinv[idx] = rsqrtf((float)(c[i] + 1));   // +1 self loop
            run += c[i];
        }
    }
    if (blockIdx.x == 0 && t == 0) rowptr[n] = e_total;
}

__global__ __launch_bounds__(256) void k_fill(const int* __restrict__ row,
                                              const int* __restrict__ col,
                                              int* __restrict__ cursor,
                                              int* __restrict__ srcidx, int e) {
    int i = blockIdx.x * 256 + threadIdx.x;
    if (i < e) {
        int p = atomicAdd(&cursor[col[i]], 1);
        srcidx[p] = row[i];
    }
}

// Transpose all 5 GCN weights: WT[j][d] = W[d][j].  W1:128x64, W2..W5:64x64.
__global__ __launch_bounds__(256) void k_transp(const float* __restrict__ W1,
                                                const float* __restrict__ W2,
                                                const float* __restrict__ W3,
                                                const float* __restrict__ W4,
                                                const float* __restrict__ W5,
                                                float* __restrict__ WT) {
    int i = blockIdx.x * 256 + threadIdx.x;
    if (i < 8192) {
        int j = i >> 7, d = i & 127;
        WT[i] = W1[d * 64 + j];
    } else if (i < 24576) {
        int q = i - 8192;
        int w = q >> 12, r = q & 4095;
        int j = r >> 6, d = r & 63;
        const float* Ws = (w == 0) ? W2 : (w == 1) ? W3 : (w == 2) ? W4 : W5;
        WT[i] = Ws[d * 64 + j];
    }
}

// GEMM: hWs[node] = (relu?(X[node]) * dinv[node]) @ W.
// W rows in LDS with r&7 XOR swizzle: w-read quad = (d4^(lane&7))&7 spans all
// 8 bank-quads -> 8-way b128 floor (old ((r>>4)&3)<<2 variant was 32-way).
template<int D, bool RELU>
__global__ __launch_bounds__(256) void k_gemm2(const float* __restrict__ X,
                                               const float* __restrict__ WT,
                                               const float* __restrict__ dinv,
                                               float* __restrict__ hWs, int n) {
    constexpr int D4 = D / 4;
    __shared__ float Wls[64 * D];
    __shared__ float Xls[32 * D];
    const int t = threadIdx.x;
    const int node0 = blockIdx.x * 32;
    float4* Wl4 = (float4*)Wls;
    float4* Xl4 = (float4*)Xls;

    for (int i = t; i < 64 * D4; i += 256) {
        int r = i / D4, d4 = i % D4;
        Wl4[r * D4 + (d4 ^ (r & 7))] = ((const float4*)WT)[i];
    }
    for (int i = t; i < 32 * D4; i += 256) {
        int nd = i / D4, d4 = i % D4;
        float4 v = make_float4(0.f, 0.f, 0.f, 0.f);
        int node = node0 + nd;
        if (node < n) {
            v = ((const float4*)X)[(size_t)node * D4 + d4];
            if (RELU) {
                v.x = fmaxf(v.x, 0.f); v.y = fmaxf(v.y, 0.f);
                v.z = fmaxf(v.z, 0.f); v.w = fmaxf(v.w, 0.f);
            }
            float di = dinv[node];
            v.x *= di; v.y *= di; v.z *= di; v.w *= di;
        }
        Xl4[i] = v;
    }
    __syncthreads();

    const int wv = t >> 6, lane = t & 63;
    const int sw = lane & 7;
    float acc[8];
    #pragma unroll
    for (int q = 0; q < 8; q++) acc[q] = 0.f;

    #pragma unroll 4
    for (int d4 = 0; d4 < D4; d4++) {
        float4 w = Wl4[lane * D4 + (d4 ^ sw)];
        #pragma unroll
        for (int q = 0; q < 8; q++) {
            float4 xv = Xl4[(wv * 8 + q) * D4 + d4];
            acc[q] = fmaf(xv.w, w.w, fmaf(xv.z, w.z, fmaf(xv.y, w.y, fmaf(xv.x, w.x, acc[q]))));
        }
    }
    #pragma unroll
    for (int q = 0; q < 8; q++) {
        int node = node0 + wv * 8 + q;
        if (node < n) hWs[(size_t)node * 64 + lane] = acc[q];
    }
}

// Gather: agg[c] = (sum_{in-edges} hWs[src] + hWs[c]) * dinv[c] + b.
// Wave per node; lane = (edge-slot 0..3, feat4 0..15). 2-way unrolled with
// dual accumulators: 2 independent srcidx->H4 chains in flight per wave.
__global__ __launch_bounds__(256) void k_gather(const int* __restrict__ rowptr,
                                                const int* __restrict__ srcidx,
                                                const float* __restrict__ dinv,
                                                const float* __restrict__ b,
                                                const float* __restrict__ hWs,
                                                float* __restrict__ agg, int n) {
    const int t = threadIdx.x;
    int w = (blockIdx.x * 256 + t) >> 6;
    if (w >= n) return;
    w = __builtin_amdgcn_readfirstlane(w);
    const int lane = t & 63;
    const int f4 = lane & 15;
    const int es = lane >> 4;
    const float4* H4 = (const float4*)hWs;
    const int s = rowptr[w], e = rowptr[w + 1];
    float4 acc0 = make_float4(0.f, 0.f, 0.f, 0.f);
    float4 acc1 = make_float4(0.f, 0.f, 0.f, 0.f);
    if (es == 0) acc0 = H4[(size_t)w * 16 + f4];   // self loop
    int i = s + es;
    for (; i + 4 < e; i += 8) {
        int s0 = srcidx[i];
        int s1 = srcidx[i + 4];
        float4 v0 = H4[(size_t)s0 * 16 + f4];
        float4 v1 = H4[(size_t)s1 * 16 + f4];
        acc0.x += v0.x; acc0.y += v0.y; acc0.z += v0.z; acc0.w += v0.w;
        acc1.x += v1.x; acc1.y += v1.y; acc1.z += v1.z; acc1.w += v1.w;
    }
    if (i < e) {
        int s0 = srcidx[i];
        float4 v0 = H4[(size_t)s0 * 16 + f4];
        acc0.x += v0.x; acc0.y += v0.y; acc0.z += v0.z; acc0.w += v0.w;
    }
    acc0.x += acc1.x; acc0.y += acc1.y; acc0.z += acc1.z; acc0.w += acc1.w;
    #pragma unroll
    for (int off = 16; off < 64; off <<= 1) {
        acc0.x += __shfl_xor(acc0.x, off);
        acc0.y += __shfl_xor(acc0.y, off);
        acc0.z += __shfl_xor(acc0.z, off);
        acc0.w += __shfl_xor(acc0.w, off);
    }
    if (es == 0) {
        float di = dinv[w];
        float4 bv = ((const float4*)b)[f4];
        float4 o;
        o.x = fmaf(acc0.x, di, bv.x);
        o.y = fmaf(acc0.y, di, bv.y);
        o.z = fmaf(acc0.z, di, bv.z);
        o.w = fmaf(acc0.w, di, bv.w);
        ((float4*)agg)[(size_t)w * 16 + f4] = o;
    }
}

__device__ __forceinline__ float sigm(float x) { return 1.f / (1.f + __expf(-x)); }
__device__ __forceinline__ float tanhf_(float x) { return 1.f - 2.f / (__expf(2.f * x) + 1.f); }

// LSTM + FC, v2. Block 256 = 4 waves, 32 nodes (8/wave); lane owns k={lane,64+lane}.
// LDS exactly 40960 B -> 4 blocks/CU. Gate weights in 8-way-floor XOR-swizzled
// LDS (r&7). FC via h1->LDS (132-stride pad) + 320 broadcast dot products.
__global__ __launch_bounds__(256) void k_lstm_fc(const float* __restrict__ agg,
                                                 const float* __restrict__ W_ih,
                                                 const float* __restrict__ b_ih,
                                                 const float* __restrict__ b_hh,
                                                 const float* __restrict__ W_fc,
                                                 const float* __restrict__ b_fc,
                                                 float* __restrict__ out, int n) {
    __shared__ float smem[10240];          // 40 KB exactly
    float4* Wl4 = (float4*)smem;           // phase1: [128 r][16 f4] swizzled (32 KB)
    float4* hN4 = (float4*)(smem + 8192);  // phase1: [32 nd][16 f4] (8 KB)
    // phase2 (after sync): h1s = smem[0..4223] ([32 nd][132 pad]), wfcs = smem[4224..5503]
    const int t = threadIdx.x;
    const int wv = t >> 6, lane = t & 63;
    const int node0 = blockIdx.x * 32;
    const float4* A4 = (const float4*)agg;
    const float4* Wih4 = (const float4*)W_ih;

    // combined biases (gates i,g,o = W_ih rows 0,256,384; k = lane, 64+lane)
    const float bi0 = b_ih[lane]       + b_hh[lane];
    const float bi1 = b_ih[64 + lane]  + b_hh[64 + lane];
    const float bg0 = b_ih[256 + lane] + b_hh[256 + lane];
    const float bg1 = b_ih[320 + lane] + b_hh[320 + lane];
    const float bo0 = b_ih[384 + lane] + b_hh[384 + lane];
    const float bo1 = b_ih[448 + lane] + b_hh[448 + lane];

    // stage node features (relu of agg)
    for (int i = t; i < 512; i += 256) {
        int nd = i >> 4;
        float4 v = make_float4(0.f, 0.f, 0.f, 0.f);
        if (node0 + nd < n) {
            v = A4[(size_t)(node0 + nd) * 16 + (i & 15)];
            v.x = fmaxf(v.x, 0.f); v.y = fmaxf(v.y, 0.f);
            v.z = fmaxf(v.z, 0.f); v.w = fmaxf(v.w, 0.f);
        }
        hN4[i] = v;
    }

    float ac[3][2][8];
    #pragma unroll
    for (int g = 0; g < 3; g++)
        #pragma unroll
        for (int h = 0; h < 2; h++)
            #pragma unroll
            for (int q = 0; q < 8; q++) ac[g][h][q] = 0.f;

    const int sw = lane & 7;
    #pragma unroll
    for (int g = 0; g < 3; g++) {
        __syncthreads();
        const int grow0 = (g == 0) ? 0 : ((g + 1) * 128);
        for (int i = t; i < 2048; i += 256) {
            int r = i >> 4, d4 = i & 15;
            Wl4[(r << 4) | (d4 ^ (r & 7))] = Wih4[(size_t)(grow0 + r) * 16 + d4];
        }
        __syncthreads();
        #pragma unroll 2
        for (int j = 0; j < 16; j++) {
            int js = j ^ sw;
            float4 w0 = Wl4[(lane << 4) | js];
            float4 w1 = Wl4[((64 + lane) << 4) | js];
            #pragma unroll
            for (int q = 0; q < 8; q++) {
                float4 hv = hN4[((wv * 8 + q) << 4) | j];
                ac[g][0][q] = fmaf(hv.w, w0.w, fmaf(hv.z, w0.z, fmaf(hv.y, w0.y, fmaf(hv.x, w0.x, ac[g][0][q]))));
                ac[g][1][q] = fmaf(hv.w, w1.w, fmaf(hv.z, w1.z, fmaf(hv.y, w1.y, fmaf(hv.x, w1.x, ac[g][1][q]))));
            }
        }
    }

    __syncthreads();   // gate reads done; smem free for h1s / wfcs

    #pragma unroll
    for (int q = 0; q < 8; q++) {
        int nd = wv * 8 + q;
        float gi0 = ac[0][0][q] + bi0, gg0 = ac[1][0][q] + bg0, go0 = ac[2][0][q] + bo0;
        float gi1 = ac[0][1][q] + bi1, gg1 = ac[1][1][q] + bg1, go1 = ac[2][1][q] + bo1;
        float h1a = sigm(go0) * tanhf_(sigm(gi0) * tanhf_(gg0));
        float h1b = sigm(go1) * tanhf_(sigm(gi1) * tanhf_(gg1));
        smem[nd * 132 + lane]      = h1a;   // k = lane
        smem[nd * 132 + 64 + lane] = h1b;   // k = 64+lane
    }
    float* wfcs = smem + 4224;
    for (int i = t; i < 1280; i += 256) wfcs[i] = W_fc[i];
    __syncthreads();

    // FC: 320 outputs (32 nodes x 10 classes); h1s rows padded to 132 words.
    for (int oc = t; oc < 320; oc += 256) {
        int nd = oc & 31, c = oc >> 5;
        const float4* hrow = (const float4*)&smem[nd * 132];
        const float4* wrow = (const float4*)&wfcs[c * 128];
        float s = 0.f;
        #pragma unroll 8
        for (int k4 = 0; k4 < 32; k4++) {
            float4 h = hrow[k4], w = wrow[k4];
            s = fmaf(h.w, w.w, fmaf(h.z, w.z, fmaf(h.y, w.y, fmaf(h.x, w.x, s))));
        }
        int node = node0 + nd;
        if (node < n) out[(size_t)node * 10 + c] = s + b_fc[c];
    }
}

extern "C" void kernel_launch(void* const* d_in, const int* in_sizes, int n_in,
                              void* d_out, int out_size, void* d_ws, size_t ws_size,
                              hipStream_t stream) {
    const float* x    = (const float*)d_in[0];
    const int*   ei   = (const int*)d_in[1];
    const float* W1   = (const float*)d_in[2];
    const float* b1   = (const float*)d_in[3];
    const float* W2   = (const float*)d_in[4];
    const float* b2   = (const float*)d_in[5];
    const float* W3   = (const float*)d_in[6];
    const float* b3   = (const float*)d_in[7];
    const float* W4   = (const float*)d_in[8];
    const float* b4   = (const float*)d_in[9];
    const float* W5   = (const float*)d_in[10];
    const float* b5   = (const float*)d_in[11];
    const float* W_ih = (const float*)d_in[12];
    // d_in[13] = W_hh: dead (h0 = 0)
    const float* b_ih = (const float*)d_in[14];
    const float* b_hh = (const float*)d_in[15];
    const float* W_fc = (const float*)d_in[16];
    const float* b_fc = (const float*)d_in[17];
    float* out = (float*)d_out;

    const int N = in_sizes[0] / 128;
    const int E = in_sizes[1] / 2;
    const int* row = ei;
    const int* col = ei + E;

    // workspace layout (4-byte units, each region 16B-aligned)
    size_t off = 0;
    auto alloc = [&](size_t elems) { size_t cur = off; off += (elems + 3) & ~(size_t)3; return cur; };
    int*   base_i = (int*)d_ws;
    float* base_f = (float*)d_ws;
    int*   cnt    = base_i + alloc(N);
    int*   rowptr = base_i + alloc((size_t)N + 1);
    int*   cursor = base_i + alloc(N);
    int*   srcidx = base_i + alloc(E);
    int*   bsum   = base_i + alloc(64);
    int*   boff   = base_i + alloc(64);
    float* dinv   = base_f + alloc(N);
    float* WT     = base_f + alloc(24576);
    float* hWs    = base_f + alloc((size_t)N * 64);
    float* agg    = base_f + alloc((size_t)N * 64);
    float* WT1 = WT;
    float* WT2 = WT + 8192;
    float* WT3 = WT + 8192 + 4096;
    float* WT4 = WT + 8192 + 8192;
    float* WT5 = WT + 8192 + 12288;

    const int nbE  = (E + 255) / 256;        // 3125
    const int nbGa = (N * 64 + 255) / 256;   // 12500 (wave per node)
    const int nbGe = (N + 31) / 32;          // 1563
    const int nbL  = (N + 31) / 32;          // 1563 (lstm v2: 32 nodes/block)
    const int nbS  = (N + 1023) / 1024;      // 49 (must be <= 64)

    hipMemsetAsync(cnt, 0, sizeof(int) * N, stream);
    k_transp<<<96, 256, 0, stream>>>(W1, W2, W3, W4, W5, WT);
    k_count<<<nbE, 256, 0, stream>>>(col, cnt, E);
    k_scanA<<<nbS, 256, 0, stream>>>(cnt, bsum, N);
    k_scanB<<<1, 64, 0, stream>>>(bsum, boff, nbS);
    k_scanC<<<nbS, 256, 0, stream>>>(cnt, boff, rowptr, cursor, dinv, N, E);
    k_fill<<<nbE, 256, 0, stream>>>(row, col, cursor, srcidx, E);

    k_gemm2<128, false><<<nbGe, 256, 0, stream>>>(x, WT1, dinv, hWs, N);
    k_gather<<<nbGa, 256, 0, stream>>>(rowptr, srcidx, dinv, b1, hWs, agg, N);
    k_gemm2<64, true><<<nbGe, 256, 0, stream>>>(agg, WT2, dinv, hWs, N);
    k_gather<<<nbGa, 256, 0, stream>>>(rowptr, srcidx, dinv, b2, hWs, agg, N);
    k_gemm2<64, true><<<nbGe, 256, 0, stream>>>(agg, WT3, dinv, hWs, N);
    k_gather<<<nbGa, 256, 0, stream>>>(rowptr, srcidx, dinv, b3, hWs, agg, N);
    k_gemm2<64, true><<<nbGe, 256, 0, stream>>>(agg, WT4, dinv, hWs, N);
    k_gather<<<nbGa, 256, 0, stream>>>(rowptr, srcidx, dinv, b4, hWs, agg, N);
    k_gemm2<64, true><<<nbGe, 256, 0, stream>>>(agg, WT5, dinv, hWs, N);
    k_gather<<<nbGa, 256, 0, stream>>>(rowptr, srcidx, dinv, b5, hWs, agg, N);

    k_lstm_fc<<<nbL, 256, 0, stream>>>(agg, W_ih, b_ih, b_hh, W_fc, b_fc, out, N);
}